// Round 17
// baseline (110.999 us; speedup 1.0000x reference)
//
#include <hip/hip_runtime.h>

// SpatialAttention B=4 HW=4096 C=256 NH=4 d=64 — f16 MFMA flash attention.
// R21 (= R20 + K-direct-from-L2): additive ledger MFMA 89K + LDS 59K + VALU
// 12K; half the LDS term is K redundancy (each 8KB K-tile staged then read
// back by 4 waves = 32KB ds_read). K is L2-resident (2MB/XCD via the XCD
// decode), so kf is now loaded straight from global into registers (VMEM
// pipe, ~7 TB/s aggregate demand vs 34.5 ceiling), one window ahead (~5600
// cyc covers ~200cyc L2 latency). K staging + K LDS reads deleted; LDS sets
// are V-only (16KB x 4 = 64KB; pool 72KB incl. epilogue). Global K read is
// the LDS XOR round-trip identity: Khat[key0+par*64+l15+16kt][quad*8|32+..].
// vmcnt ledger: compiler's kf-wait each window drains all older loads ->
// V(w) landed block-wide before the barrier; manual waits 12/10/8.
// All else R20: G=4, 8-wave K-parity split, c-major COMPUTE, fixed-bias
// exp2(S-8) via QK C-init, ones-row MFMA l-sum (AGPR side), stride-68 pad.

#define HW 4096
#define CCH 256
#define DH 64
#define NH 4
#define QTILE 256
#define KTILE 64
#define LOG2E 1.44269504088896340736f

typedef __attribute__((ext_vector_type(8))) _Float16 half8;
typedef __attribute__((ext_vector_type(4))) _Float16 half4;
typedef __attribute__((ext_vector_type(2))) __fp16 pk16x2;   // cvt_pkrtz native type
typedef __attribute__((ext_vector_type(4))) float floatx4;

typedef __attribute__((address_space(1))) const unsigned int gbl_u32;
typedef __attribute__((address_space(3))) unsigned int lds_u32;

__device__ __forceinline__ void gload_lds16(const void* g, void* l) {
    __builtin_amdgcn_global_load_lds((gbl_u32*)g, (lds_u32*)l, 16, 0, 0);
}
__device__ __forceinline__ floatx4 mfma_k32(half8 a, half8 b, floatx4 c) {
    return __builtin_amdgcn_mfma_f32_16x16x32_f16(a, b, c, 0, 0, 0);
}

// ---------- fused prepass ----------
// blocks [0,4096): Qhat/Khat elementwise (scale*log2e folded into Q).
// Khat rows permuted within each 32-key chunk (see R9): aligns QK^T C/D row
// map with the k32 PV B-frag k-map, zero cross-lane traffic.
// blocks [4096,5120): Vthat transpose [B*NH][64][HW] (physical key order)
__global__ __launch_bounds__(256) void prepass_all(
    const float* __restrict__ q_in, const float* __restrict__ k_in,
    const float* __restrict__ v_in,
    const float* __restrict__ wq, const float* __restrict__ bq,
    const float* __restrict__ wk, const float* __restrict__ bk,
    const float* __restrict__ wv, const float* __restrict__ bv,
    _Float16* __restrict__ Qhat, _Float16* __restrict__ Khat,
    _Float16* __restrict__ Vthat)
{
    if (blockIdx.x < 4096) {
        int idx = (blockIdx.x * 256 + threadIdx.x) * 4;
        int b = idx >> 20;
        int rem = idx & ((1 << 20) - 1);
        int row = rem >> 8;
        int c = rem & 255;
        int h = c >> 6;
        int ch = c & 63;
        floatx4 q4 = *(const floatx4*)(q_in + idx);
        floatx4 k4 = *(const floatx4*)(k_in + idx);
        floatx4 wq4 = *(const floatx4*)(wq + c);
        floatx4 bq4 = *(const floatx4*)(bq + c);
        floatx4 wk4 = *(const floatx4*)(wk + c);
        floatx4 bk4 = *(const floatx4*)(bk + c);
        const float qsc = 0.125f * LOG2E;
        half4 qh, kh;
        qh[0] = (_Float16)((q4.x * wq4.x + bq4.x) * qsc);
        qh[1] = (_Float16)((q4.y * wq4.y + bq4.y) * qsc);
        qh[2] = (_Float16)((q4.z * wq4.z + bq4.z) * qsc);
        qh[3] = (_Float16)((q4.w * wq4.w + bq4.w) * qsc);
        kh[0] = (_Float16)(k4.x * wk4.x + bk4.x);
        kh[1] = (_Float16)(k4.y * wk4.y + bk4.y);
        kh[2] = (_Float16)(k4.z * wk4.z + bk4.z);
        kh[3] = (_Float16)(k4.w * wk4.w + bk4.w);
        size_t o_q = ((size_t)(b * NH + h) * HW + row) * DH + ch;
        int p = row & 31;
        int srow = ((p & 4) << 2) + ((p >> 3) << 2) + (p & 3);
        int row_k = (row & ~31) | srow;
        size_t o_k = ((size_t)(b * NH + h) * HW + row_k) * DH + ch;
        *(half4*)(Qhat + o_q) = qh;
        *(half4*)(Khat + o_k) = kh;
    } else {
        __shared__ _Float16 Lt[64 * 68];
        int bx = blockIdx.x - 4096;
        int t = threadIdx.x;
        int key0 = (bx & 63) * 64;
        int bh = bx >> 6;
        int b = bh >> 2, h = bh & 3;
        int c4 = (t & 15) * 4;
        floatx4 wv4 = *(const floatx4*)(wv + h * DH + c4);
        floatx4 bv4 = *(const floatx4*)(bv + h * DH + c4);
        #pragma unroll
        for (int p = 0; p < 4; ++p) {
            int key = p * 16 + (t >> 4);
            const float* vp = v_in + ((size_t)b * HW + key0 + key) * CCH + h * DH + c4;
            floatx4 v4 = *(const floatx4*)vp;
            half4 vh;
            vh[0] = (_Float16)(v4.x * wv4.x + bv4.x);
            vh[1] = (_Float16)(v4.y * wv4.y + bv4.y);
            vh[2] = (_Float16)(v4.z * wv4.z + bv4.z);
            vh[3] = (_Float16)(v4.w * wv4.w + bv4.w);
            *(half4*)(&Lt[key * 68 + c4]) = vh;
        }
        __syncthreads();
        #pragma unroll
        for (int p = 0; p < 2; ++p) {
            int ch = p * 32 + (t >> 3);
            int kg = (t & 7) * 8;
            half8 v8;
            #pragma unroll
            for (int j = 0; j < 8; ++j) v8[j] = Lt[(kg + j) * 68 + ch];
            *(half8*)(Vthat + ((size_t)bh * DH + ch) * HW + key0 + kg) = v8;
        }
    }
}

// ---------- attention (G=4, K-parity split, K-from-L2, V-only LDS) ----------
__launch_bounds__(512, 2)
__global__ void attn_kernel(
    const _Float16* __restrict__ Qhat, const _Float16* __restrict__ Khat,
    const _Float16* __restrict__ Vthat,
    const float* __restrict__ wp, const float* __restrict__ bp,
    float* __restrict__ out)
{
    // pool: 4 V-sets x 16KB {Vev 8K | Vod 8K} = 64KB
    // epilogue: P1 [4][64][68] f32 @0 (69632B), Pl @69632, Ot @0
    __shared__ alignas(16) char pool[73728];

    const int tid = threadIdx.x;
    const int wave = tid >> 6;      // 0..7
    const int lane = tid & 63;
    const int l15 = lane & 15;
    const int quad = lane >> 4;
    const int ksw = l15 & 7;
    const int qw = wave & 3;        // q-group (64 rows each)
    const int par = wave >> 2;      // K-tile parity

    // XCD-locality decode: XCD x = f&7 gets bh {2x, 2x+1}
    const int f = blockIdx.x;
    const int xcd = f & 7;
    const int s = f >> 3;           // 0..31
    const int bh = 2 * xcd + (s >> 4);
    const int qtile = s & 15;

    // Q B-frags: 4 groups of 16 q-rows (64 rows/wave)
    const int q0 = qtile * QTILE + qw * 64;
    half8 qfrag[4][2];
    #pragma unroll
    for (int g = 0; g < 4; ++g) {
        const _Float16* qp = Qhat + ((size_t)bh * HW + q0 + g * 16 + l15) * DH + quad * 8;
        qfrag[g][0] = *(const half8*)(qp);
        qfrag[g][1] = *(const half8*)(qp + 32);
    }

    // V staging lane addresses (XOR swizzle of 8-half groups in global addr)
    const int srow0 = lane >> 3;
    const int sw = (lane & 7) ^ srow0;
    const _Float16* vgp = Vthat + ((size_t)bh * DH + wave * 8 + srow0) * HW + sw * 8;

    // K direct-from-global base: row (par*64 + l15), ch-group quad
    const _Float16* kbase = Khat + ((size_t)bh * HW + par * 64 + l15) * DH + quad * 8;

    half8 ones8;
    #pragma unroll
    for (int j = 0; j < 8; ++j) ones8[j] = (_Float16)1.0f;

    floatx4 acc[4][4];
    floatx4 accl[4];
    #pragma unroll
    for (int g = 0; g < 4; ++g) {
        floatx4 z = {0.f,0.f,0.f,0.f};
        accl[g] = z;
        #pragma unroll
        for (int nt = 0; nt < 4; ++nt) acc[g][nt] = z;
    }

    half8 kf[4][2];   // current window's K fragments (prefetched from L2)

    #define STAGE(st, SP) do {                                                 \
        const size_t voff = (size_t)(st) * 128;                                \
        gload_lds16(vgp + voff,      (SP) + wave * 1024);                      \
        gload_lds16(vgp + voff + 64, (SP) + 8192 + wave * 1024);               \
    } while (0)

    // K for super-tile st, straight from global (L2-resident)
    #define LOADK(st) do {                                                     \
        const _Float16* Kb = kbase + (size_t)(st) * 128 * DH;                  \
        _Pragma("unroll")                                                      \
        for (int kt = 0; kt < 4; ++kt) {                                       \
            kf[kt][0] = *(const half8*)(Kb + kt * 16 * DH);                    \
            kf[kt][1] = *(const half8*)(Kb + kt * 16 * DH + 32);               \
        }                                                                      \
    } while (0)

    // one c-slice: QK (kt = 2c, 2c+1) -> exp2 -> pfrag -> accl + PV
    #define HALF_TILE(c, VB) do {                                              \
        half8 pfrag[4];                                                        \
        __builtin_amdgcn_s_setprio(1);                                         \
        _Pragma("unroll")                                                      \
        for (int g = 0; g < 4; ++g) {                                          \
            floatx4 sa = {-8.f,-8.f,-8.f,-8.f};                                \
            floatx4 sb = sa;                                                   \
            sa = mfma_k32(kf[2*(c)][0], qfrag[g][0], sa);                      \
            sa = mfma_k32(kf[2*(c)][1], qfrag[g][1], sa);                      \
            sb = mfma_k32(kf[2*(c)+1][0], qfrag[g][0], sb);                    \
            sb = mfma_k32(kf[2*(c)+1][1], qfrag[g][1], sb);                    \
            float a0 = __builtin_amdgcn_exp2f(sa[0]);                          \
            float a1 = __builtin_amdgcn_exp2f(sa[1]);                          \
            float a2 = __builtin_amdgcn_exp2f(sa[2]);                          \
            float a3 = __builtin_amdgcn_exp2f(sa[3]);                          \
            float b0 = __builtin_amdgcn_exp2f(sb[0]);                          \
            float b1 = __builtin_amdgcn_exp2f(sb[1]);                          \
            float b2 = __builtin_amdgcn_exp2f(sb[2]);                          \
            float b3 = __builtin_amdgcn_exp2f(sb[3]);                          \
            pk16x2 p01 = __builtin_amdgcn_cvt_pkrtz(a0, a1);                   \
            pk16x2 p23 = __builtin_amdgcn_cvt_pkrtz(a2, a3);                   \
            pk16x2 p45 = __builtin_amdgcn_cvt_pkrtz(b0, b1);                   \
            pk16x2 p67 = __builtin_amdgcn_cvt_pkrtz(b2, b3);                   \
            half8 pk;                                                          \
            pk[0] = (_Float16)p01[0]; pk[1] = (_Float16)p01[1];                \
            pk[2] = (_Float16)p23[0]; pk[3] = (_Float16)p23[1];                \
            pk[4] = (_Float16)p45[0]; pk[5] = (_Float16)p45[1];                \
            pk[6] = (_Float16)p67[0]; pk[7] = (_Float16)p67[1];                \
            pfrag[g] = pk;                                                     \
        }                                                                      \
        _Pragma("unroll")                                                      \
        for (int g = 0; g < 4; ++g)                                            \
            accl[g] = mfma_k32(ones8, pfrag[g], accl[g]);                      \
        _Pragma("unroll")                                                      \
        for (int nt = 0; nt < 4; ++nt) {                                       \
            const _Float16* vr = (VB) + (l15 + 16 * nt) * 64                   \
                + ((((c) * 4 + quad) ^ ksw) * 8);                              \
            half8 vf = *(const half8*)vr;                                      \
            _Pragma("unroll")                                                  \
            for (int g = 0; g < 4; ++g)                                        \
                acc[g][nt] = mfma_k32(vf, pfrag[g], acc[g][nt]);               \
        }                                                                      \
        __builtin_amdgcn_s_setprio(0);                                         \
    } while (0)

    // window: HALF(c0) -> HALF(c1 GEN) with LOADK(next) between kf-death & PV
    #define COMPUTE(SPcur, nextst, DO_NEXT) do {                               \
        const _Float16* VB = (const _Float16*)((SPcur) + par * 8192);          \
        HALF_TILE(0, VB);                                                      \
        {                                                                      \
            half8 pfrag[4];                                                    \
            __builtin_amdgcn_s_setprio(1);                                     \
            _Pragma("unroll")                                                  \
            for (int g = 0; g < 4; ++g) {                                      \
                floatx4 sa = {-8.f,-8.f,-8.f,-8.f};                            \
                floatx4 sb = sa;                                               \
                sa = mfma_k32(kf[2][0], qfrag[g][0], sa);                      \
                sa = mfma_k32(kf[2][1], qfrag[g][1], sa);                      \
                sb = mfma_k32(kf[3][0], qfrag[g][0], sb);                      \
                sb = mfma_k32(kf[3][1], qfrag[g][1], sb);                      \
                float a0 = __builtin_amdgcn_exp2f(sa[0]);                      \
                float a1 = __builtin_amdgcn_exp2f(sa[1]);                      \
                float a2 = __builtin_amdgcn_exp2f(sa[2]);                      \
                float a3 = __builtin_amdgcn_exp2f(sa[3]);                      \
                float b0 = __builtin_amdgcn_exp2f(sb[0]);                      \
                float b1 = __builtin_amdgcn_exp2f(sb[1]);                      \
                float b2 = __builtin_amdgcn_exp2f(sb[2]);                      \
                float b3 = __builtin_amdgcn_exp2f(sb[3]);                      \
                pk16x2 p01 = __builtin_amdgcn_cvt_pkrtz(a0, a1);               \
                pk16x2 p23 = __builtin_amdgcn_cvt_pkrtz(a2, a3);               \
                pk16x2 p45 = __builtin_amdgcn_cvt_pkrtz(b0, b1);               \
                pk16x2 p67 = __builtin_amdgcn_cvt_pkrtz(b2, b3);               \
                half8 pk;                                                      \
                pk[0] = (_Float16)p01[0]; pk[1] = (_Float16)p01[1];            \
                pk[2] = (_Float16)p23[0]; pk[3] = (_Float16)p23[1];            \
                pk[4] = (_Float16)p45[0]; pk[5] = (_Float16)p45[1];            \
                pk[6] = (_Float16)p67[0]; pk[7] = (_Float16)p67[1];            \
                pfrag[g] = pk;                                                 \
            }                                                                  \
            __builtin_amdgcn_s_setprio(0);                                     \
            if (DO_NEXT) LOADK(nextst);  /* kf dead; hides under PV below */   \
            __builtin_amdgcn_s_setprio(1);                                     \
            _Pragma("unroll")                                                  \
            for (int g = 0; g < 4; ++g)                                        \
                accl[g] = mfma_k32(ones8, pfrag[g], accl[g]);                  \
            _Pragma("unroll")                                                  \
            for (int nt = 0; nt < 4; ++nt) {                                   \
                const _Float16* vr = VB + (l15 + 16 * nt) * 64                 \
                    + (((4 + quad) ^ ksw) * 8);                                \
                half8 vf = *(const half8*)vr;                                  \
                _Pragma("unroll")                                              \
                for (int g = 0; g < 4; ++g)                                    \
                    acc[g][nt] = mfma_k32(vf, pfrag[g], acc[g][nt]);           \
            }                                                                  \
            __builtin_amdgcn_s_setprio(0);                                     \
        }                                                                      \
    } while (0)

    #define WAITVM(n) asm volatile("s_waitcnt vmcnt(" #n ")" ::: "memory")
    #define BARS() do { __builtin_amdgcn_s_barrier();                          \
                        __builtin_amdgcn_sched_barrier(0); } while (0)

    char* set0 = pool;
    char* set1 = pool + 16384;
    char* set2 = pool + 32768;
    char* set3 = pool + 49152;

    // window w: V from set[w&3] (staged at w-3), K from kf (loaded from L2
    // during window w-1). The compiler's vmcnt-wait before each window's kf
    // use drains all older loads -> V(w) landed block-wide before barrier(w).
    // STAGE(w+3) overwrites set[(w-1)&3] (readers done before barrier w).
    STAGE(0, set0);
    STAGE(1, set1);
    STAGE(2, set2);
    LOADK(0);
    // w0: outstanding S0:2,S1:2,S2:2,K0:8 = 14 -> drain S0 (V0 ready)
    WAITVM(12); BARS();
    STAGE(3, set3);
    COMPUTE(set0, 1, 1);
    // w = 1..28 (7 packs of 4)
    for (int t = 1; t <= 25; t += 4) {
        WAITVM(10); BARS(); STAGE(t + 3, set0); COMPUTE(set1, t + 1, 1);
        WAITVM(10); BARS(); STAGE(t + 4, set1); COMPUTE(set2, t + 2, 1);
        WAITVM(10); BARS(); STAGE(t + 5, set2); COMPUTE(set3, t + 3, 1);
        WAITVM(10); BARS(); STAGE(t + 6, set3); COMPUTE(set0, t + 4, 1);
    }
    // w29 (V29 in set1; K(30) prefetch)
    WAITVM(10); BARS(); COMPUTE(set1, 30, 1);
    // w30 (V30 in set2; K(31) prefetch)
    WAITVM(8);  BARS(); COMPUTE(set2, 31, 1);
    // w31 (V31 in set3; no further loads)
    WAITVM(8);  BARS(); COMPUTE(set3, 0, 0);

    // ---- merge K-parity partials (pure adds: same fixed bias), store ----
    const int b = bh >> 2, h = bh & 3, ch0 = h * DH;
    float* P1 = (float*)pool;                    // [4 qw][64 q][68] f32
    float* Pl = (float*)(pool + 69632);          // [4 qw][64 q]

    __syncthreads();
    if (par == 1) {
        #pragma unroll
        for (int g = 0; g < 4; ++g) {
            #pragma unroll
            for (int nt = 0; nt < 4; ++nt)
                *(floatx4*)&P1[qw * 4352 + (g * 16 + l15) * 68 + nt * 16 + quad * 4] = acc[g][nt];
            if (quad == 0) {
                Pl[qw * 64 + g * 16 + l15] = accl[g][0];
            }
        }
    }
    __syncthreads();
    if (par == 0) {
        #pragma unroll
        for (int g = 0; g < 4; ++g) {
            float lB = Pl[qw * 64 + g * 16 + l15];
            float inv = 1.0f / (accl[g][0] + lB);
            #pragma unroll
            for (int nt = 0; nt < 4; ++nt) {
                floatx4 vB = *(const floatx4*)&P1[qw * 4352 + (g * 16 + l15) * 68 + nt * 16 + quad * 4];
                #pragma unroll
                for (int r = 0; r < 4; ++r)
                    acc[g][nt][r] = (acc[g][nt][r] + vB[r]) * inv;
            }
        }
    }
    __syncthreads();
    if (par == 0) {
        floatx4 wp4 = *(const floatx4*)(wp + ch0 + l15 * 4);
        floatx4 bp4 = *(const floatx4*)(bp + ch0 + l15 * 4);
        float* Ot = (float*)(pool) + qw * 2304;  // [32 q][72] floats
        #pragma unroll
        for (int p = 0; p < 2; ++p) {
            #pragma unroll
            for (int gg = 0; gg < 2; ++gg) {
                int g = p * 2 + gg;
                #pragma unroll
                for (int nt = 0; nt < 4; ++nt)
                    *(floatx4*)&Ot[(gg * 16 + l15) * 72 + nt * 16 + quad * 4] = acc[g][nt];
            }
            #pragma unroll
            for (int i = 0; i < 8; ++i) {
                int q = i * 4 + quad;
                floatx4 v = *(const floatx4*)&Ot[q * 72 + l15 * 4];
                floatx4 o;
                o.x = v.x * wp4.x + bp4.x;
                o.y = v.y * wp4.y + bp4.y;
                o.z = v.z * wp4.z + bp4.z;
                o.w = v.w * wp4.w + bp4.w;
                *(floatx4*)(out + ((size_t)b * HW + q0 + p * 32 + q) * CCH + ch0 + l15 * 4) = o;
            }
        }
    }
    #undef STAGE
    #undef LOADK
    #undef HALF_TILE
    #undef COMPUTE
    #undef WAITVM
    #undef BARS
}

extern "C" void kernel_launch(void* const* d_in, const int* in_sizes, int n_in,
                              void* d_out, int out_size, void* d_ws, size_t ws_size,
                              hipStream_t stream) {
    const float* q_in = (const float*)d_in[0];
    const float* k_in = (const float*)d_in[1];
    const float* v_in = (const float*)d_in[2];
    const float* wq = (const float*)d_in[3];
    const float* bq = (const float*)d_in[4];
    const float* wk = (const float*)d_in[5];
    const float* bk = (const float*)d_in[6];
    const float* wv = (const float*)d_in[7];
    const float* bv = (const float*)d_in[8];
    const float* wp = (const float*)d_in[9];
    const float* bp = (const float*)d_in[10];
    float* out = (float*)d_out;

    const size_t tensor_halves = (size_t)4 * NH * HW * DH;
    _Float16* Qhat = (_Float16*)d_ws;
    _Float16* Khat = Qhat + tensor_halves;
    _Float16* Vthat = Khat + tensor_halves;

    prepass_all<<<dim3(4096 + 1024), 256, 0, stream>>>(
        q_in, k_in, v_in, wq, bq, wk, bk, wv, bv, Qhat, Khat, Vthat);
    attn_kernel<<<dim3(HW / QTILE * 4 * NH), 512, 0, stream>>>(
        Qhat, Khat, Vthat, wp, bp, out);
}

// Round 18
// 82.201 us; speedup vs baseline: 1.3503x; 1.3503x over previous
//
#include <hip/hip_runtime.h>

// SpatialAttention B=4 HW=4096 C=256 NH=4 d=64 — f16 MFMA flash attention.
// FINAL = R17/R20 (session best: 82.4us verified twice, VGPR 116, no spill).
// Session findings: time = ~90%-additive pipe sum (MFMA 89K + LDS 59K +
// VALU 12K cyc/CU); only instruction-count reduction moved it (122.6 ->
// 82.4us). Falsified: occupancy >2waves/SIMD (R6/R7), cache locality as
// limiter (R10: FETCH -5.6x, time -2%), intra-wave pipelining (R11),
// phase-stagger (R15/R18: VGPR spill), VALU l-sum (R19: AGPR->VGPR side
// shift = 1.17GB scratch), K-direct-from-L2 (R21: exposed VMEM latency,
// LDS staging is the latency-hiding mechanism). Structure: G=4 (64 q-rows/
// wave), 8-wave K-parity split (2 waves/SIMD), c-major COMPUTE (one pfrag
// half live), K-reg prefetch between kf-death and PV burst, 4-set LDS
// rotation + distance-3 counted vmcnt(4), XCD-locality decode, fixed-bias
// softmax exp2(S-8) folded into QK C-init, ones-row MFMA l-sum (AGPR),
// R9 Khat permutation (QK C/D rows == k32 PV B-frag keys), stride-68 pad.

#define HW 4096
#define CCH 256
#define DH 64
#define NH 4
#define QTILE 256
#define KTILE 64
#define LOG2E 1.44269504088896340736f

typedef __attribute__((ext_vector_type(8))) _Float16 half8;
typedef __attribute__((ext_vector_type(4))) _Float16 half4;
typedef __attribute__((ext_vector_type(2))) __fp16 pk16x2;   // cvt_pkrtz native type
typedef __attribute__((ext_vector_type(4))) float floatx4;

typedef __attribute__((address_space(1))) const unsigned int gbl_u32;
typedef __attribute__((address_space(3))) unsigned int lds_u32;

__device__ __forceinline__ void gload_lds16(const void* g, void* l) {
    __builtin_amdgcn_global_load_lds((gbl_u32*)g, (lds_u32*)l, 16, 0, 0);
}
__device__ __forceinline__ floatx4 mfma_k32(half8 a, half8 b, floatx4 c) {
    return __builtin_amdgcn_mfma_f32_16x16x32_f16(a, b, c, 0, 0, 0);
}

// ---------- fused prepass ----------
// blocks [0,4096): Qhat/Khat elementwise (scale*log2e folded into Q).
// Khat rows permuted within each 32-key chunk (see R9): aligns QK^T C/D row
// map with the k32 PV B-frag k-map, zero cross-lane traffic.
// blocks [4096,5120): Vthat transpose [B*NH][64][HW] (physical key order)
__global__ __launch_bounds__(256) void prepass_all(
    const float* __restrict__ q_in, const float* __restrict__ k_in,
    const float* __restrict__ v_in,
    const float* __restrict__ wq, const float* __restrict__ bq,
    const float* __restrict__ wk, const float* __restrict__ bk,
    const float* __restrict__ wv, const float* __restrict__ bv,
    _Float16* __restrict__ Qhat, _Float16* __restrict__ Khat,
    _Float16* __restrict__ Vthat)
{
    if (blockIdx.x < 4096) {
        int idx = (blockIdx.x * 256 + threadIdx.x) * 4;
        int b = idx >> 20;
        int rem = idx & ((1 << 20) - 1);
        int row = rem >> 8;
        int c = rem & 255;
        int h = c >> 6;
        int ch = c & 63;
        floatx4 q4 = *(const floatx4*)(q_in + idx);
        floatx4 k4 = *(const floatx4*)(k_in + idx);
        floatx4 wq4 = *(const floatx4*)(wq + c);
        floatx4 bq4 = *(const floatx4*)(bq + c);
        floatx4 wk4 = *(const floatx4*)(wk + c);
        floatx4 bk4 = *(const floatx4*)(bk + c);
        const float qsc = 0.125f * LOG2E;
        half4 qh, kh;
        qh[0] = (_Float16)((q4.x * wq4.x + bq4.x) * qsc);
        qh[1] = (_Float16)((q4.y * wq4.y + bq4.y) * qsc);
        qh[2] = (_Float16)((q4.z * wq4.z + bq4.z) * qsc);
        qh[3] = (_Float16)((q4.w * wq4.w + bq4.w) * qsc);
        kh[0] = (_Float16)(k4.x * wk4.x + bk4.x);
        kh[1] = (_Float16)(k4.y * wk4.y + bk4.y);
        kh[2] = (_Float16)(k4.z * wk4.z + bk4.z);
        kh[3] = (_Float16)(k4.w * wk4.w + bk4.w);
        size_t o_q = ((size_t)(b * NH + h) * HW + row) * DH + ch;
        int p = row & 31;
        int srow = ((p & 4) << 2) + ((p >> 3) << 2) + (p & 3);
        int row_k = (row & ~31) | srow;
        size_t o_k = ((size_t)(b * NH + h) * HW + row_k) * DH + ch;
        *(half4*)(Qhat + o_q) = qh;
        *(half4*)(Khat + o_k) = kh;
    } else {
        __shared__ _Float16 Lt[64 * 68];
        int bx = blockIdx.x - 4096;
        int t = threadIdx.x;
        int key0 = (bx & 63) * 64;
        int bh = bx >> 6;
        int b = bh >> 2, h = bh & 3;
        int c4 = (t & 15) * 4;
        floatx4 wv4 = *(const floatx4*)(wv + h * DH + c4);
        floatx4 bv4 = *(const floatx4*)(bv + h * DH + c4);
        #pragma unroll
        for (int p = 0; p < 4; ++p) {
            int key = p * 16 + (t >> 4);
            const float* vp = v_in + ((size_t)b * HW + key0 + key) * CCH + h * DH + c4;
            floatx4 v4 = *(const floatx4*)vp;
            half4 vh;
            vh[0] = (_Float16)(v4.x * wv4.x + bv4.x);
            vh[1] = (_Float16)(v4.y * wv4.y + bv4.y);
            vh[2] = (_Float16)(v4.z * wv4.z + bv4.z);
            vh[3] = (_Float16)(v4.w * wv4.w + bv4.w);
            *(half4*)(&Lt[key * 68 + c4]) = vh;
        }
        __syncthreads();
        #pragma unroll
        for (int p = 0; p < 2; ++p) {
            int ch = p * 32 + (t >> 3);
            int kg = (t & 7) * 8;
            half8 v8;
            #pragma unroll
            for (int j = 0; j < 8; ++j) v8[j] = Lt[(kg + j) * 68 + ch];
            *(half8*)(Vthat + ((size_t)bh * DH + ch) * HW + key0 + kg) = v8;
        }
    }
}

// ---------- attention (G=4, K-parity split, c-major, K-reg prefetch) ----------
__launch_bounds__(512, 2)
__global__ void attn_kernel(
    const _Float16* __restrict__ Qhat, const _Float16* __restrict__ Khat,
    const _Float16* __restrict__ Vthat,
    const float* __restrict__ wp, const float* __restrict__ bp,
    float* __restrict__ out)
{
    // pool: 4 sets x 32KB {Kev 8K | Kod 8K | Vev 8K | Vod 8K}
    // epilogue: P1 [4][64][68] f32 @0 (69632B), Pl @69632, Ot @0
    __shared__ alignas(16) char pool[131072];

    const int tid = threadIdx.x;
    const int wave = tid >> 6;      // 0..7
    const int lane = tid & 63;
    const int l15 = lane & 15;
    const int quad = lane >> 4;
    const int ksw = l15 & 7;
    const int qw = wave & 3;        // q-group (64 rows each)
    const int par = wave >> 2;      // K-tile parity

    // XCD-locality decode: XCD x = f&7 gets bh {2x, 2x+1}
    const int f = blockIdx.x;
    const int xcd = f & 7;
    const int s = f >> 3;           // 0..31
    const int bh = 2 * xcd + (s >> 4);
    const int qtile = s & 15;

    // Q B-frags: 4 groups of 16 q-rows (64 rows/wave)
    const int q0 = qtile * QTILE + qw * 64;
    half8 qfrag[4][2];
    #pragma unroll
    for (int g = 0; g < 4; ++g) {
        const _Float16* qp = Qhat + ((size_t)bh * HW + q0 + g * 16 + l15) * DH + quad * 8;
        qfrag[g][0] = *(const half8*)(qp);
        qfrag[g][1] = *(const half8*)(qp + 32);
    }

    // staging lane addresses (XOR swizzle of 8-half groups in global addr)
    const int srow0 = lane >> 3;
    const int sw = (lane & 7) ^ srow0;
    const _Float16* kgp = Khat + ((size_t)bh * HW + wave * 8 + srow0) * DH + sw * 8;
    const _Float16* vgp = Vthat + ((size_t)bh * DH + wave * 8 + srow0) * HW + sw * 8;

    half8 ones8;
    #pragma unroll
    for (int j = 0; j < 8; ++j) ones8[j] = (_Float16)1.0f;

    floatx4 acc[4][4];
    floatx4 accl[4];
    #pragma unroll
    for (int g = 0; g < 4; ++g) {
        floatx4 z = {0.f,0.f,0.f,0.f};
        accl[g] = z;
        #pragma unroll
        for (int nt = 0; nt < 4; ++nt) acc[g][nt] = z;
    }

    half8 kf[4][2];   // current window's K fragments (prefetched, 32 VGPR)

    #define STAGE(st, SP) do {                                                 \
        const size_t koff = (size_t)(st) * 128 * DH;                           \
        const size_t voff = (size_t)(st) * 128;                                \
        gload_lds16(kgp + koff,           (SP) + wave * 1024);                 \
        gload_lds16(kgp + koff + 64 * DH, (SP) + 8192 + wave * 1024);          \
        gload_lds16(vgp + voff,           (SP) + 16384 + wave * 1024);         \
        gload_lds16(vgp + voff + 64,      (SP) + 24576 + wave * 1024);         \
    } while (0)

    #define LOADK(SP) do {                                                     \
        const _Float16* KBn = (const _Float16*)((SP) + par * 8192);            \
        _Pragma("unroll")                                                      \
        for (int kt = 0; kt < 4; ++kt) {                                       \
            const _Float16* kr = KBn + (l15 + 16 * kt) * 64;                   \
            kf[kt][0] = *(const half8*)(kr + ((quad ^ ksw) * 8));              \
            kf[kt][1] = *(const half8*)(kr + (((4 + quad) ^ ksw) * 8));        \
        }                                                                      \
    } while (0)

    // one c-slice: QK (kt = 2c, 2c+1) -> exp2 -> pfrag -> accl + PV
    #define HALF_TILE(c, VB) do {                                              \
        half8 pfrag[4];                                                        \
        __builtin_amdgcn_s_setprio(1);                                         \
        _Pragma("unroll")                                                      \
        for (int g = 0; g < 4; ++g) {                                          \
            floatx4 sa = {-8.f,-8.f,-8.f,-8.f};                                \
            floatx4 sb = sa;                                                   \
            sa = mfma_k32(kf[2*(c)][0], qfrag[g][0], sa);                      \
            sa = mfma_k32(kf[2*(c)][1], qfrag[g][1], sa);                      \
            sb = mfma_k32(kf[2*(c)+1][0], qfrag[g][0], sb);                    \
            sb = mfma_k32(kf[2*(c)+1][1], qfrag[g][1], sb);                    \
            float a0 = __builtin_amdgcn_exp2f(sa[0]);                          \
            float a1 = __builtin_amdgcn_exp2f(sa[1]);                          \
            float a2 = __builtin_amdgcn_exp2f(sa[2]);                          \
            float a3 = __builtin_amdgcn_exp2f(sa[3]);                          \
            float b0 = __builtin_amdgcn_exp2f(sb[0]);                          \
            float b1 = __builtin_amdgcn_exp2f(sb[1]);                          \
            float b2 = __builtin_amdgcn_exp2f(sb[2]);                          \
            float b3 = __builtin_amdgcn_exp2f(sb[3]);                          \
            pk16x2 p01 = __builtin_amdgcn_cvt_pkrtz(a0, a1);                   \
            pk16x2 p23 = __builtin_amdgcn_cvt_pkrtz(a2, a3);                   \
            pk16x2 p45 = __builtin_amdgcn_cvt_pkrtz(b0, b1);                   \
            pk16x2 p67 = __builtin_amdgcn_cvt_pkrtz(b2, b3);                   \
            half8 pk;                                                          \
            pk[0] = (_Float16)p01[0]; pk[1] = (_Float16)p01[1];                \
            pk[2] = (_Float16)p23[0]; pk[3] = (_Float16)p23[1];                \
            pk[4] = (_Float16)p45[0]; pk[5] = (_Float16)p45[1];                \
            pk[6] = (_Float16)p67[0]; pk[7] = (_Float16)p67[1];                \
            pfrag[g] = pk;                                                     \
        }                                                                      \
        _Pragma("unroll")                                                      \
        for (int g = 0; g < 4; ++g)                                            \
            accl[g] = mfma_k32(ones8, pfrag[g], accl[g]);                      \
        _Pragma("unroll")                                                      \
        for (int nt = 0; nt < 4; ++nt) {                                       \
            const _Float16* vr = (VB) + (l15 + 16 * nt) * 64                   \
                + ((((c) * 4 + quad) ^ ksw) * 8);                              \
            half8 vf = *(const half8*)vr;                                      \
            _Pragma("unroll")                                                  \
            for (int g = 0; g < 4; ++g)                                        \
                acc[g][nt] = mfma_k32(vf, pfrag[g], acc[g][nt]);               \
        }                                                                      \
        __builtin_amdgcn_s_setprio(0);                                         \
    } while (0)

    // window: HALF(c0) -> HALF(c1 GEN) with LOADK(next) between kf-death & PV
    #define COMPUTE(SPcur, SPnext, DO_NEXT) do {                               \
        const _Float16* VB = (const _Float16*)((SPcur) + 16384 + par * 8192);  \
        HALF_TILE(0, VB);                                                      \
        {                                                                      \
            half8 pfrag[4];                                                    \
            __builtin_amdgcn_s_setprio(1);                                     \
            _Pragma("unroll")                                                  \
            for (int g = 0; g < 4; ++g) {                                      \
                floatx4 sa = {-8.f,-8.f,-8.f,-8.f};                            \
                floatx4 sb = sa;                                               \
                sa = mfma_k32(kf[2][0], qfrag[g][0], sa);                      \
                sa = mfma_k32(kf[2][1], qfrag[g][1], sa);                      \
                sb = mfma_k32(kf[3][0], qfrag[g][0], sb);                      \
                sb = mfma_k32(kf[3][1], qfrag[g][1], sb);                      \
                float a0 = __builtin_amdgcn_exp2f(sa[0]);                      \
                float a1 = __builtin_amdgcn_exp2f(sa[1]);                      \
                float a2 = __builtin_amdgcn_exp2f(sa[2]);                      \
                float a3 = __builtin_amdgcn_exp2f(sa[3]);                      \
                float b0 = __builtin_amdgcn_exp2f(sb[0]);                      \
                float b1 = __builtin_amdgcn_exp2f(sb[1]);                      \
                float b2 = __builtin_amdgcn_exp2f(sb[2]);                      \
                float b3 = __builtin_amdgcn_exp2f(sb[3]);                      \
                pk16x2 p01 = __builtin_amdgcn_cvt_pkrtz(a0, a1);               \
                pk16x2 p23 = __builtin_amdgcn_cvt_pkrtz(a2, a3);               \
                pk16x2 p45 = __builtin_amdgcn_cvt_pkrtz(b0, b1);               \
                pk16x2 p67 = __builtin_amdgcn_cvt_pkrtz(b2, b3);               \
                half8 pk;                                                      \
                pk[0] = (_Float16)p01[0]; pk[1] = (_Float16)p01[1];            \
                pk[2] = (_Float16)p23[0]; pk[3] = (_Float16)p23[1];            \
                pk[4] = (_Float16)p45[0]; pk[5] = (_Float16)p45[1];            \
                pk[6] = (_Float16)p67[0]; pk[7] = (_Float16)p67[1];            \
                pfrag[g] = pk;                                                 \
            }                                                                  \
            __builtin_amdgcn_s_setprio(0);                                     \
            if (DO_NEXT) LOADK(SPnext);  /* kf dead; hides under PV below */   \
            __builtin_amdgcn_s_setprio(1);                                     \
            _Pragma("unroll")                                                  \
            for (int g = 0; g < 4; ++g)                                        \
                accl[g] = mfma_k32(ones8, pfrag[g], accl[g]);                  \
            _Pragma("unroll")                                                  \
            for (int nt = 0; nt < 4; ++nt) {                                   \
                const _Float16* vr = VB + (l15 + 16 * nt) * 64                 \
                    + (((4 + quad) ^ ksw) * 8);                                \
                half8 vf = *(const half8*)vr;                                  \
                _Pragma("unroll")                                              \
                for (int g = 0; g < 4; ++g)                                    \
                    acc[g][nt] = mfma_k32(vf, pfrag[g], acc[g][nt]);           \
            }                                                                  \
            __builtin_amdgcn_s_setprio(0);                                     \
        }                                                                      \
    } while (0)

    #define WAITVM(n) asm volatile("s_waitcnt vmcnt(" #n ")" ::: "memory")
    #define BARS() do { __builtin_amdgcn_s_barrier();                          \
                        __builtin_amdgcn_sched_barrier(0); } while (0)

    char* set0 = pool;
    char* set1 = pool + 32768;
    char* set2 = pool + 65536;
    char* set3 = pool + 98304;

    // window w: V from set[w&3], K from kf (loaded in window w-1 from
    // set[w&3]); LOADK(set[(w+1)&3]) valid after barrier(w) (distance-3:
    // WAITVM(4) drains own stage(w+1) -> all waves' stage(w+1) landed at
    // barrier). STAGE(w+3) overwrites set[(w-1)&3] (no window-w readers).
    STAGE(0, set0);
    STAGE(1, set1);
    STAGE(2, set2);
    WAITVM(8); BARS();     // stage0 landed globally
    LOADK(set0);
    // w = 0..27 (7 packs of 4)
    for (int t = 0; t < 28; t += 4) {
        WAITVM(4); BARS(); STAGE(t + 3, set3); COMPUTE(set0, set1, 1);
        WAITVM(4); BARS(); STAGE(t + 4, set0); COMPUTE(set1, set2, 1);
        WAITVM(4); BARS(); STAGE(t + 5, set1); COMPUTE(set2, set3, 1);
        WAITVM(4); BARS(); STAGE(t + 6, set2); COMPUTE(set3, set0, 1);
    }
    // w=28
    WAITVM(4); BARS(); STAGE(31, set3); COMPUTE(set0, set1, 1);
    // w=29 (stage30 landed here; LOADK set2)
    WAITVM(4); BARS(); COMPUTE(set1, set2, 1);
    // w=30 (drain stage31 for LOADK set3)
    WAITVM(0); BARS(); COMPUTE(set2, set3, 1);
    // w=31 (all data landed globally after w=30's barrier)
    COMPUTE(set3, set0, 0);

    // ---- merge K-parity partials (pure adds: same fixed bias), store ----
    const int b = bh >> 2, h = bh & 3, ch0 = h * DH;
    float* P1 = (float*)pool;                    // [4 qw][64 q][68] f32
    float* Pl = (float*)(pool + 69632);          // [4 qw][64 q]

    __syncthreads();
    if (par == 1) {
        #pragma unroll
        for (int g = 0; g < 4; ++g) {
            #pragma unroll
            for (int nt = 0; nt < 4; ++nt)
                *(floatx4*)&P1[qw * 4352 + (g * 16 + l15) * 68 + nt * 16 + quad * 4] = acc[g][nt];
            if (quad == 0) {
                Pl[qw * 64 + g * 16 + l15] = accl[g][0];
            }
        }
    }
    __syncthreads();
    if (par == 0) {
        #pragma unroll
        for (int g = 0; g < 4; ++g) {
            float lB = Pl[qw * 64 + g * 16 + l15];
            float inv = 1.0f / (accl[g][0] + lB);
            #pragma unroll
            for (int nt = 0; nt < 4; ++nt) {
                floatx4 vB = *(const floatx4*)&P1[qw * 4352 + (g * 16 + l15) * 68 + nt * 16 + quad * 4];
                #pragma unroll
                for (int r = 0; r < 4; ++r)
                    acc[g][nt][r] = (acc[g][nt][r] + vB[r]) * inv;
            }
        }
    }
    __syncthreads();
    if (par == 0) {
        floatx4 wp4 = *(const floatx4*)(wp + ch0 + l15 * 4);
        floatx4 bp4 = *(const floatx4*)(bp + ch0 + l15 * 4);
        float* Ot = (float*)(pool) + qw * 2304;  // [32 q][72] floats
        #pragma unroll
        for (int p = 0; p < 2; ++p) {
            #pragma unroll
            for (int gg = 0; gg < 2; ++gg) {
                int g = p * 2 + gg;
                #pragma unroll
                for (int nt = 0; nt < 4; ++nt)
                    *(floatx4*)&Ot[(gg * 16 + l15) * 72 + nt * 16 + quad * 4] = acc[g][nt];
            }
            #pragma unroll
            for (int i = 0; i < 8; ++i) {
                int q = i * 4 + quad;
                floatx4 v = *(const floatx4*)&Ot[q * 72 + l15 * 4];
                floatx4 o;
                o.x = v.x * wp4.x + bp4.x;
                o.y = v.y * wp4.y + bp4.y;
                o.z = v.z * wp4.z + bp4.z;
                o.w = v.w * wp4.w + bp4.w;
                *(floatx4*)(out + ((size_t)b * HW + q0 + p * 32 + q) * CCH + ch0 + l15 * 4) = o;
            }
        }
    }
    #undef STAGE
    #undef LOADK
    #undef HALF_TILE
    #undef COMPUTE
    #undef WAITVM
    #undef BARS
}

extern "C" void kernel_launch(void* const* d_in, const int* in_sizes, int n_in,
                              void* d_out, int out_size, void* d_ws, size_t ws_size,
                              hipStream_t stream) {
    const float* q_in = (const float*)d_in[0];
    const float* k_in = (const float*)d_in[1];
    const float* v_in = (const float*)d_in[2];
    const float* wq = (const float*)d_in[3];
    const float* bq = (const float*)d_in[4];
    const float* wk = (const float*)d_in[5];
    const float* bk = (const float*)d_in[6];
    const float* wv = (const float*)d_in[7];
    const float* bv = (const float*)d_in[8];
    const float* wp = (const float*)d_in[9];
    const float* bp = (const float*)d_in[10];
    float* out = (float*)d_out;

    const size_t tensor_halves = (size_t)4 * NH * HW * DH;
    _Float16* Qhat = (_Float16*)d_ws;
    _Float16* Khat = Qhat + tensor_halves;
    _Float16* Vthat = Khat + tensor_halves;

    prepass_all<<<dim3(4096 + 1024), 256, 0, stream>>>(
        q_in, k_in, v_in, wq, bq, wk, bk, wv, bv, Qhat, Khat, Vthat);
    attn_kernel<<<dim3(HW / QTILE * 4 * NH), 512, 0, stream>>>(
        Qhat, Khat, Vthat, wp, bp, out);
}